// Round 16
// baseline (321.952 us; speedup 1.0000x reference)
//
#include <hip/hip_runtime.h>
#include <hip/hip_fp16.h>
#include <math.h>

#define NODES 50000
#define NEDGES 800000
#define TOT_E (NEDGES + NODES)
#define SCAN_B 256
#define SCAN_NB ((NODES + SCAN_B - 1) / SCAN_B)

typedef __attribute__((ext_vector_type(8))) _Float16 half8v;
typedef __attribute__((ext_vector_type(4))) float f32x4;

union U2H { uint u; __half2 h; };

static __device__ __forceinline__ float lrelu(float z) {
  return z > 0.f ? z : 0.2f * z;
}
static __device__ __forceinline__ ushort f2h(float f) {
  __half h = __float2half_rn(f);
  return *reinterpret_cast<ushort*>(&h);
}
static __device__ __forceinline__ void wave_lds_fence() {
  __builtin_amdgcn_wave_barrier();
  asm volatile("s_waitcnt lgkmcnt(0)" ::: "memory");
  __builtin_amdgcn_sched_barrier(0);
}

// ---------------- fused setup: hist + cast + packB x3 ----------------
static __device__ __forceinline__ void packB_one(const float* __restrict__ W,
    ushort* __restrict__ Bp, int N, int NF, int idx) {
  int i = idx & 7;
  int lane = (idx >> 3) & 63;
  int rem = idx >> 9;
  int nf = rem % NF;
  int kf = rem / NF;
  int k = kf * 32 + (lane >> 4) * 8 + i;
  int col = nf * 16 + (lane & 15);
  float v = (col < N) ? W[(size_t)k * N + col] : 0.f;
  Bp[idx] = f2h(v);
}

__global__ __launch_bounds__(256) void k_setup(const int* __restrict__ dst,
    int* __restrict__ counts, const float* __restrict__ x, ushort* __restrict__ xb0,
    const float* __restrict__ W0, ushort* __restrict__ Bp0,
    const float* __restrict__ W1, ushort* __restrict__ Bp1,
    const float* __restrict__ W2, ushort* __restrict__ Bp2) {
  int gb = blockIdx.x;
  int tid = threadIdx.x;
  if (gb < 2048) {
    int stride = 2048 * 256;
    for (int i = gb * 256 + tid; i < TOT_E; i += stride) {
      int d = (i < NEDGES) ? dst[i] : (i - NEDGES);
      atomicAdd(&counts[d], 1);
    }
  } else if (gb < 4048) {
    int total4 = NODES * 128 / 4;
    int stride = 2000 * 256;
    for (int i = (gb - 2048) * 256 + tid; i < total4; i += stride) {
      float4 v = *(const float4*)&x[i * 4];
      ushort4 o;
      o.x = f2h(v.x); o.y = f2h(v.y); o.z = f2h(v.z); o.w = f2h(v.w);
      *(ushort4*)&xb0[i * 4] = o;
    }
  } else {
    int b = gb - 4048;
    int stride = 48 * 256;
    int base = b * 256 + tid;
    for (int idx = base; idx < 4 * 16 * 512; idx += stride) packB_one(W0, Bp0, 256, 16, idx);
    for (int idx = base; idx < 8 * 16 * 512; idx += stride) packB_one(W1, Bp1, 256, 16, idx);
    for (int idx = base; idx < 8 * 3 * 512; idx += stride)  packB_one(W2, Bp2, 40, 3, idx);
  }
}

// ---------------- CSR scan (red+part fused via last-block) + emit + scatter ----------------
__global__ __launch_bounds__(SCAN_B) void k_scan_red_part(const int* __restrict__ counts,
    int* __restrict__ bsum, int* __restrict__ bpre, int* __restrict__ done) {
  __shared__ int sm[SCAN_B];
  __shared__ int lastflag;
  int idx = blockIdx.x * SCAN_B + threadIdx.x;
  int v = (idx < NODES) ? counts[idx] : 0;
  sm[threadIdx.x] = v;
  __syncthreads();
  for (int off = SCAN_B / 2; off > 0; off >>= 1) {
    if (threadIdx.x < off) sm[threadIdx.x] += sm[threadIdx.x + off];
    __syncthreads();
  }
  if (threadIdx.x == 0) {
    __hip_atomic_store(&bsum[blockIdx.x], sm[0], __ATOMIC_RELEASE, __HIP_MEMORY_SCOPE_AGENT);
    int t = __hip_atomic_fetch_add(done, 1, __ATOMIC_ACQ_REL, __HIP_MEMORY_SCOPE_AGENT);
    lastflag = (t == (int)gridDim.x - 1);
  }
  __syncthreads();
  if (!lastflag) return;
  int tid = threadIdx.x;
  int b = (tid < SCAN_NB)
      ? __hip_atomic_load(&bsum[tid], __ATOMIC_ACQUIRE, __HIP_MEMORY_SCOPE_AGENT) : 0;
  __syncthreads();
  sm[tid] = b;
  __syncthreads();
  for (int off = 1; off < 256; off <<= 1) {
    int t2 = (tid >= off) ? sm[tid - off] : 0;
    __syncthreads();
    sm[tid] += t2;
    __syncthreads();
  }
  if (tid < SCAN_NB) bpre[tid] = sm[tid] - b;  // exclusive
}

__global__ __launch_bounds__(SCAN_B) void k_scan_emit(const int* __restrict__ counts,
    const int* __restrict__ bpre, int* __restrict__ offs, int* __restrict__ cur) {
  __shared__ int sm[SCAN_B];
  int idx = blockIdx.x * SCAN_B + threadIdx.x;
  int tid = threadIdx.x;
  int v = (idx < NODES) ? counts[idx] : 0;
  sm[tid] = v;
  __syncthreads();
  for (int off = 1; off < SCAN_B; off <<= 1) {
    int t = (tid >= off) ? sm[tid - off] : 0;
    __syncthreads();
    sm[tid] += t;
    __syncthreads();
  }
  int base = bpre[blockIdx.x];
  int excl = base + sm[tid] - v;
  if (idx < NODES) { offs[idx] = excl; cur[idx] = excl; }
  if (idx == NODES - 1) offs[NODES] = excl + v;
}

__global__ void k_scatter(const int* __restrict__ src, const int* __restrict__ dst,
                          int* __restrict__ cur, ushort* __restrict__ ssrc) {
  int stride = gridDim.x * blockDim.x;
  for (int i = blockIdx.x * blockDim.x + threadIdx.x; i < TOT_E; i += stride) {
    int s, d;
    if (i < NEDGES) { s = src[i]; d = dst[i]; } else { s = i - NEDGES; d = s; }
    int pos = atomicAdd(&cur[d], 1);
    ssrc[pos] = (ushort)s;
  }
}

// ---------------- register-resident-B MFMA GEMM (f16) + fused logits ----------------
template<int KF, int NFW, int CG, int HEADS, int NF_TOT>
__global__ __launch_bounds__(256, 2) void k_gemm_reg(
    const ushort* __restrict__ A, const ushort* __restrict__ Bp,
    ushort* __restrict__ H, const float* __restrict__ a_s, const float* __restrict__ a_d,
    float* __restrict__ al_s, float* __restrict__ al_d, int M, int N, int K) {
  int wib = threadIdx.x >> 6;
  int lane = threadIdx.x & 63;
  int lg = lane >> 4;
  int lr = lane & 15;
  int cg, strip0, sstride;
  if (CG == 4) { cg = wib; strip0 = blockIdx.x; sstride = gridDim.x; }
  else { cg = 0; strip0 = blockIdx.x * 4 + wib; sstride = gridDim.x * 4; }

  half8v b[KF][NFW];
#pragma unroll
  for (int kf = 0; kf < KF; ++kf)
#pragma unroll
    for (int n = 0; n < NFW; ++n)
      b[kf][n] = *(const half8v*)(Bp + ((size_t)(kf * NF_TOT + cg * NFW + n) * 64 + lane) * 8);

  float asc[NFW], adc[NFW];
#pragma unroll
  for (int n = 0; n < NFW; ++n) {
    int col = (cg * NFW + n) * 16 + lr;
    bool ok = col < N;
    asc[n] = ok ? a_s[col] : 0.f;
    adc[n] = ok ? a_d[col] : 0.f;
  }

  int nstrips = M >> 4;
  for (int strip = strip0; strip < nstrips; strip += sstride) {
    const ushort* arow = A + (size_t)(strip * 16 + lr) * K + lg * 8;
    half8v a[KF];
#pragma unroll
    for (int kf = 0; kf < KF; ++kf) a[kf] = *(const half8v*)(arow + kf * 32);
    f32x4 acc[NFW];
#pragma unroll
    for (int n = 0; n < NFW; ++n) acc[n] = (f32x4){0.f, 0.f, 0.f, 0.f};
#pragma unroll
    for (int kf = 0; kf < KF; ++kf)
#pragma unroll
      for (int n = 0; n < NFW; ++n)
        acc[n] = __builtin_amdgcn_mfma_f32_16x16x32_f16(a[kf], b[kf][n], acc[n], 0, 0, 0);

#pragma unroll
    for (int n = 0; n < NFW; ++n) {
      int col = (cg * NFW + n) * 16 + lr;
      if (col < N) {
#pragma unroll
        for (int r = 0; r < 4; ++r) {
          int row = strip * 16 + lg * 4 + r;
          H[(size_t)row * N + col] = f2h(acc[n][r]);
        }
      }
    }

    float ps[4], pd[4];
#pragma unroll
    for (int r = 0; r < 4; ++r) {
      float s = 0.f, d = 0.f;
#pragma unroll
      for (int n = 0; n < NFW; ++n) {
        s += acc[n][r] * asc[n];
        d += acc[n][r] * adc[n];
      }
      ps[r] = s; pd[r] = d;
    }
#pragma unroll
    for (int off = 1; off <= 8; off <<= 1)
#pragma unroll
      for (int t = 0; t < 4; ++t) {
        ps[t] += __shfl_xor(ps[t], off);
        pd[t] += __shfl_xor(pd[t], off);
      }
    if (lr < 4) {
      int row = strip * 16 + lg * 4 + lr;
      if (HEADS == 4) {
        al_s[row * 4 + cg] = ps[lr];
        al_d[row * 4 + cg] = pd[lr];
      } else {
        al_s[row] = ps[lr];
        al_d[row] = pd[lr];
      }
    }
  }
}

// ---------------- aggregation: 4-way head split, half-wave per (node, head) --------
// head = (blockIdx&7)>>1 -> each head served by an XCD pair; per-XCD gather
// footprint 6.4MB (one 128B line per edge). 32 lanes: es = l>>3 edge slot (4),
// c = l&7 -> 16B of the 128B head-row. 2-deep unroll -> 8 edges in flight.
__global__ __launch_bounds__(256) void k_agg4(const ushort* __restrict__ hb,
    const float* __restrict__ al_s, const float* __restrict__ al_d,
    const int* __restrict__ offs, const ushort* __restrict__ ssrc,
    const float* __restrict__ bias, ushort* __restrict__ outb) {
  __shared__ uint s_sv[8][32];
  __shared__ uint s_al[8][32];
  int bid = blockIdx.x;
  int head = (bid & 7) >> 1;
  int nb = (bid >> 3) * 2 + (bid & 1);
  int hw = threadIdx.x >> 5;
  int node = nb * 8 + hw;
  if (node >= NODES) return;
  int l = threadIdx.x & 31;
  int beg = offs[node], end = offs[node + 1];
  float aldh = al_d[node * 4 + head];

  // pass A: single-head max
  float m = -1e30f;
  for (int i = beg + l; i < end; i += 32)
    m = fmaxf(m, lrelu(al_s[ssrc[i] * 4 + head] + aldh));
#pragma unroll
  for (int off = 1; off <= 16; off <<= 1) m = fmaxf(m, __shfl_xor(m, off));

  int es = l >> 3;                // edge slot (0..3)
  int c = l & 7;                  // 16B group within head row
  uint clb = (uint)(head * 64 + c * 8);   // element offset in full row
  float sacc = 0.f;
  __half2 z2 = __float2half2_rn(0.f);
  __half2 accA[4] = {z2, z2, z2, z2};
  __half2 accB[4] = {z2, z2, z2, z2};

  for (int cb = beg; cb < end; cb += 32) {
    int cnt = min(32, end - cb);
    wave_lds_fence();
    if (l < cnt) {
      uint sv = (uint)ssrc[cb + l];
      float t = __expf(lrelu(al_s[sv * 4 + head] + aldh) - m);
      sacc += t;
      U2H pk; pk.h = __float2half2_rn(t);
      s_sv[hw][l] = sv;
      s_al[hw][l] = pk.u;
    }
    wave_lds_fence();
    int ee = es;
    for (; ee + 7 < cnt; ee += 8) {   // 2 edges per slot in flight
      uint sv0 = s_sv[hw][ee], sv1 = s_sv[hw][ee + 4];
      U2H a0, a1;
      a0.u = s_al[hw][ee]; a1.u = s_al[hw][ee + 4];
      uint4 hv0 = *(const uint4*)(hb + ((sv0 << 8) + clb));
      uint4 hv1 = *(const uint4*)(hb + ((sv1 << 8) + clb));
      U2H v;
      v.u = hv0.x; accA[0] = __hfma2(a0.h, v.h, accA[0]);
      v.u = hv0.y; accA[1] = __hfma2(a0.h, v.h, accA[1]);
      v.u = hv0.z; accA[2] = __hfma2(a0.h, v.h, accA[2]);
      v.u = hv0.w; accA[3] = __hfma2(a0.h, v.h, accA[3]);
      v.u = hv1.x; accB[0] = __hfma2(a1.h, v.h, accB[0]);
      v.u = hv1.y; accB[1] = __hfma2(a1.h, v.h, accB[1]);
      v.u = hv1.z; accB[2] = __hfma2(a1.h, v.h, accB[2]);
      v.u = hv1.w; accB[3] = __hfma2(a1.h, v.h, accB[3]);
    }
    for (; ee < cnt; ee += 4) {
      uint sv = s_sv[hw][ee];
      U2H a0; a0.u = s_al[hw][ee];
      uint4 hv = *(const uint4*)(hb + ((sv << 8) + clb));
      U2H v;
      v.u = hv.x; accA[0] = __hfma2(a0.h, v.h, accA[0]);
      v.u = hv.y; accA[1] = __hfma2(a0.h, v.h, accA[1]);
      v.u = hv.z; accA[2] = __hfma2(a0.h, v.h, accA[2]);
      v.u = hv.w; accA[3] = __hfma2(a0.h, v.h, accA[3]);
    }
  }
#pragma unroll
  for (int off = 1; off <= 16; off <<= 1) sacc += __shfl_xor(sacc, off);
  float invs = 1.f / sacc;
  // merge 4 edge slots, normalize + bias + ELU, write 16B
  ushort4 ores[2];
#pragma unroll
  for (int j = 0; j < 4; ++j) {
    U2H t; t.h = __hadd2(accA[j], accB[j]);
    U2H o;
    o.u = __shfl_xor(t.u, 8);  t.h = __hadd2(t.h, o.h);
    o.u = __shfl_xor(t.u, 16); t.h = __hadd2(t.h, o.h);
    float lo = __low2float(t.h) * invs + bias[clb + j * 2];
    float hi = __high2float(t.h) * invs + bias[clb + j * 2 + 1];
    lo = lo > 0.f ? lo : __expf(lo) - 1.f;
    hi = hi > 0.f ? hi : __expf(hi) - 1.f;
    ((ushort*)ores)[j * 2]     = f2h(lo);
    ((ushort*)ores)[j * 2 + 1] = f2h(hi);
  }
  if (es == 0) {
    *(ushort4*)(outb + (size_t)node * 256 + clb)     = ores[0];
    *(ushort4*)(outb + (size_t)node * 256 + clb + 4) = ores[1];
  }
}

// layer 2: H=1, C=40, f16; half-wave per node, 8 edges in flight
__global__ __launch_bounds__(256) void k_agg1(const ushort* __restrict__ hb,
    const float* __restrict__ al_s, const float* __restrict__ al_d,
    const int* __restrict__ offs, const ushort* __restrict__ ssrc,
    const float* __restrict__ bias, float* __restrict__ out) {
  __shared__ uint s_sv[8][32];
  __shared__ uint s_al[8][32];
  int hw = threadIdx.x >> 5;
  int node = (blockIdx.x * 256 + threadIdx.x) >> 5;
  if (node >= NODES) return;
  int l = threadIdx.x & 31;
  int beg = offs[node], end = offs[node + 1];
  float ald = al_d[node];

  float m = -1e30f;
  for (int i = beg + l; i < end; i += 32)
    m = fmaxf(m, lrelu(al_s[ssrc[i]] + ald));
#pragma unroll
  for (int off = 1; off <= 16; off <<= 1) m = fmaxf(m, __shfl_xor(m, off));

  int p = l >> 4;
  int cq = l & 15;
  bool act = cq < 10;
  uint cqb = (uint)cq * 4;
  float sacc = 0.f;
  __half2 z2 = __float2half2_rn(0.f);
  __half2 accA[2] = {z2, z2};
  __half2 accB[2] = {z2, z2};
  for (int cb = beg; cb < end; cb += 32) {
    int cnt = min(32, end - cb);
    wave_lds_fence();
    if (l < cnt) {
      uint sv = (uint)ssrc[cb + l];
      float t = __expf(lrelu(al_s[sv] + ald) - m);
      sacc += t;
      U2H pk; pk.h = __float2half2_rn(t);
      s_sv[hw][l] = sv;
      s_al[hw][l] = pk.u;
    }
    wave_lds_fence();
    int e = p;
    for (; e + 14 < cnt; e += 16) {
      uint sv0 = s_sv[hw][e],      sv1 = s_sv[hw][e + 2];
      uint sv2 = s_sv[hw][e + 4],  sv3 = s_sv[hw][e + 6];
      uint sv4 = s_sv[hw][e + 8],  sv5 = s_sv[hw][e + 10];
      uint sv6 = s_sv[hw][e + 12], sv7 = s_sv[hw][e + 14];
      U2H a0, a1, a2, a3, a4, a5, a6, a7;
      a0.u = s_al[hw][e];      a1.u = s_al[hw][e + 2];
      a2.u = s_al[hw][e + 4];  a3.u = s_al[hw][e + 6];
      a4.u = s_al[hw][e + 8];  a5.u = s_al[hw][e + 10];
      a6.u = s_al[hw][e + 12]; a7.u = s_al[hw][e + 14];
      if (act) {
        uint2 hv0 = *(const uint2*)(hb + (sv0 * 40u + cqb));
        uint2 hv1 = *(const uint2*)(hb + (sv1 * 40u + cqb));
        uint2 hv2 = *(const uint2*)(hb + (sv2 * 40u + cqb));
        uint2 hv3 = *(const uint2*)(hb + (sv3 * 40u + cqb));
        uint2 hv4 = *(const uint2*)(hb + (sv4 * 40u + cqb));
        uint2 hv5 = *(const uint2*)(hb + (sv5 * 40u + cqb));
        uint2 hv6 = *(const uint2*)(hb + (sv6 * 40u + cqb));
        uint2 hv7 = *(const uint2*)(hb + (sv7 * 40u + cqb));
        U2H v;
        v.u = hv0.x; accA[0] = __hfma2(a0.h, v.h, accA[0]);
        v.u = hv0.y; accA[1] = __hfma2(a0.h, v.h, accA[1]);
        v.u = hv1.x; accB[0] = __hfma2(a1.h, v.h, accB[0]);
        v.u = hv1.y; accB[1] = __hfma2(a1.h, v.h, accB[1]);
        v.u = hv2.x; accA[0] = __hfma2(a2.h, v.h, accA[0]);
        v.u = hv2.y; accA[1] = __hfma2(a2.h, v.h, accA[1]);
        v.u = hv3.x; accB[0] = __hfma2(a3.h, v.h, accB[0]);
        v.u = hv3.y; accB[1] = __hfma2(a3.h, v.h, accB[1]);
        v.u = hv4.x; accA[0] = __hfma2(a4.h, v.h, accA[0]);
        v.u = hv4.y; accA[1] = __hfma2(a4.h, v.h, accA[1]);
        v.u = hv5.x; accB[0] = __hfma2(a5.h, v.h, accB[0]);
        v.u = hv5.y; accB[1] = __hfma2(a5.h, v.h, accB[1]);
        v.u = hv6.x; accA[0] = __hfma2(a6.h, v.h, accA[0]);
        v.u = hv6.y; accA[1] = __hfma2(a6.h, v.h, accA[1]);
        v.u = hv7.x; accB[0] = __hfma2(a7.h, v.h, accB[0]);
        v.u = hv7.y; accB[1] = __hfma2(a7.h, v.h, accB[1]);
      }
    }
    for (; e + 6 < cnt; e += 8) {
      uint sv0 = s_sv[hw][e],     sv1 = s_sv[hw][e + 2];
      uint sv2 = s_sv[hw][e + 4], sv3 = s_sv[hw][e + 6];
      U2H a0, a1, a2, a3;
      a0.u = s_al[hw][e];     a1.u = s_al[hw][e + 2];
      a2.u = s_al[hw][e + 4]; a3.u = s_al[hw][e + 6];
      if (act) {
        uint2 hv0 = *(const uint2*)(hb + (sv0 * 40u + cqb));
        uint2 hv1 = *(const uint2*)(hb + (sv1 * 40u + cqb));
        uint2 hv2 = *(const uint2*)(hb + (sv2 * 40u + cqb));
        uint2 hv3 = *(const uint2*)(hb + (sv3 * 40u + cqb));
        U2H v;
        v.u = hv0.x; accA[0] = __hfma2(a0.h, v.h, accA[0]);
        v.u = hv0.y; accA[1] = __hfma2(a0.h, v.h, accA[1]);
        v.u = hv1.x; accB[0] = __hfma2(a1.h, v.h, accB[0]);
        v.u = hv1.y; accB[1] = __hfma2(a1.h, v.h, accB[1]);
        v.u = hv2.x; accA[0] = __hfma2(a2.h, v.h, accA[0]);
        v.u = hv2.y; accA[1] = __hfma2(a2.h, v.h, accA[1]);
        v.u = hv3.x; accB[0] = __hfma2(a3.h, v.h, accB[0]);
        v.u = hv3.y; accB[1] = __hfma2(a3.h, v.h, accB[1]);
      }
    }
    for (; e < cnt; e += 2) {
      uint sv = s_sv[hw][e];
      U2H a0; a0.u = s_al[hw][e];
      if (act) {
        uint2 hv = *(const uint2*)(hb + (sv * 40u + cqb));
        U2H v;
        v.u = hv.x; accA[0] = __hfma2(a0.h, v.h, accA[0]);
        v.u = hv.y; accA[1] = __hfma2(a0.h, v.h, accA[1]);
      }
    }
  }
#pragma unroll
  for (int off = 1; off <= 16; off <<= 1) sacc += __shfl_xor(sacc, off);
  float invs = 1.f / sacc;
  float vv[4];
#pragma unroll
  for (int j = 0; j < 2; ++j) {
    U2H t; t.h = __hadd2(accA[j], accB[j]);
    U2H o; o.u = __shfl_xor(t.u, 16);
    t.h = __hadd2(t.h, o.h);
    vv[j * 2]     = __low2float(t.h) * invs;
    vv[j * 2 + 1] = __high2float(t.h) * invs;
  }
  float mm = -1e30f;
  if (act) {
#pragma unroll
    for (int j = 0; j < 4; ++j) {
      vv[j] += bias[cq * 4 + j];
      mm = fmaxf(mm, vv[j]);
    }
  }
#pragma unroll
  for (int off = 1; off <= 8; off <<= 1) mm = fmaxf(mm, __shfl_xor(mm, off));
  float se = 0.f;
  if (act) {
#pragma unroll
    for (int j = 0; j < 4; ++j) se += __expf(vv[j] - mm);
  }
#pragma unroll
  for (int off = 1; off <= 8; off <<= 1) se += __shfl_xor(se, off);
  if (act && p == 0) {
    float lse = mm + __logf(se);
    float4 o;
    o.x = vv[0] - lse; o.y = vv[1] - lse; o.z = vv[2] - lse; o.w = vv[3] - lse;
    *(float4*)&out[(size_t)node * 40 + cq * 4] = o;
  }
}

// ---------------- launch ----------------
extern "C" void kernel_launch(void* const* d_in, const int* in_sizes, int n_in,
                              void* d_out, int out_size, void* d_ws, size_t ws_size,
                              hipStream_t stream) {
  const float* x   = (const float*)d_in[0];
  const int*   ei  = (const int*)d_in[1];
  const float* W0  = (const float*)d_in[2];
  const float* as0 = (const float*)d_in[3];
  const float* ad0 = (const float*)d_in[4];
  const float* b0  = (const float*)d_in[5];
  const float* W1  = (const float*)d_in[6];
  const float* as1 = (const float*)d_in[7];
  const float* ad1 = (const float*)d_in[8];
  const float* b1  = (const float*)d_in[9];
  const float* W2  = (const float*)d_in[10];
  const float* as2 = (const float*)d_in[11];
  const float* ad2 = (const float*)d_in[12];
  const float* b2  = (const float*)d_in[13];
  float* out = (float*)d_out;

  char* p = (char*)d_ws;
  auto take = [&](size_t bytes) {
    char* q = p;
    p += (bytes + 255) & ~(size_t)255;
    return (void*)q;
  };
  ushort* xb0 = (ushort*)take((size_t)NODES * 128 * 2);
  ushort* xb1 = (ushort*)take((size_t)NODES * 256 * 2);
  ushort* xb2 = (ushort*)take((size_t)NODES * 256 * 2);
  ushort* hb  = (ushort*)take((size_t)NODES * 256 * 2);
  float* als  = (float*)take((size_t)NODES * 4 * 4);
  float* ald  = (float*)take((size_t)NODES * 4 * 4);
  ushort* ssrc= (ushort*)take((size_t)TOT_E * 2);
  int* offs   = (int*)take((size_t)(NODES + 1) * 4);
  int* cur    = (int*)take((size_t)NODES * 4);
  int* cnt    = (int*)take((size_t)(NODES + 64) * 4);
  int* done   = cnt + NODES;
  int* bsum   = (int*)take((size_t)SCAN_NB * 4);
  int* bpre   = (int*)take((size_t)SCAN_NB * 4);
  ushort* Bp0 = (ushort*)take((size_t)4 * 16 * 512 * 2);
  ushort* Bp1 = (ushort*)take((size_t)8 * 16 * 512 * 2);
  ushort* Bp2 = (ushort*)take((size_t)8 * 3 * 512 * 2);

  hipMemsetAsync(cnt, 0, (size_t)(NODES + 64) * 4, stream);
  k_setup<<<4096, 256, 0, stream>>>(ei + NEDGES, cnt, x, xb0, W0, Bp0, W1, Bp1, W2, Bp2);
  k_scan_red_part<<<SCAN_NB, SCAN_B, 0, stream>>>(cnt, bsum, bpre, done);
  k_scan_emit<<<SCAN_NB, SCAN_B, 0, stream>>>(cnt, bpre, offs, cur);
  k_scatter<<<4096, 256, 0, stream>>>(ei, ei + NEDGES, cur, ssrc);

  int nab = (NODES * 32 + 255) / 256;            // 6250 node-blocks (8 nodes each)
  int nab2 = (nab + 1) & ~1;                     // even for 2-way node interleave
  int nagg4 = nab2 * 4;                          // x4 heads

  // layer 0
  k_gemm_reg<4, 4, 4, 4, 16><<<512, 256, 0, stream>>>(xb0, Bp0, hb, as0, ad0, als, ald, NODES, 256, 128);
  k_agg4<<<nagg4, 256, 0, stream>>>(hb, als, ald, offs, ssrc, b0, xb1);

  // layer 1
  k_gemm_reg<8, 4, 4, 4, 16><<<512, 256, 0, stream>>>(xb1, Bp1, hb, as1, ad1, als, ald, NODES, 256, 256);
  k_agg4<<<nagg4, 256, 0, stream>>>(hb, als, ald, offs, ssrc, b1, xb2);

  // layer 2
  k_gemm_reg<8, 3, 1, 1, 3><<<512, 256, 0, stream>>>(xb2, Bp2, hb, as2, ad2, als, ald, NODES, 40, 256);
  k_agg1<<<nab, 256, 0, stream>>>(hb, als, ald, offs, ssrc, b2, out);
}

// Round 17
// 295.780 us; speedup vs baseline: 1.0885x; 1.0885x over previous
//
#include <hip/hip_runtime.h>
#include <hip/hip_fp16.h>
#include <math.h>

#define NODES 50000
#define NEDGES 800000
#define TOT_E (NEDGES + NODES)
#define SCAN_B 256
#define SCAN_NB ((NODES + SCAN_B - 1) / SCAN_B)

typedef __attribute__((ext_vector_type(8))) _Float16 half8v;
typedef __attribute__((ext_vector_type(4))) float f32x4;

union U2H { uint u; __half2 h; };

static __device__ __forceinline__ float lrelu(float z) {
  return z > 0.f ? z : 0.2f * z;
}
static __device__ __forceinline__ ushort f2h(float f) {
  __half h = __float2half_rn(f);
  return *reinterpret_cast<ushort*>(&h);
}
static __device__ __forceinline__ void wave_lds_fence() {
  __builtin_amdgcn_wave_barrier();
  asm volatile("s_waitcnt lgkmcnt(0)" ::: "memory");
  __builtin_amdgcn_sched_barrier(0);
}

// ---------------- fused setup: hist + cast + packB x3 ----------------
static __device__ __forceinline__ void packB_one(const float* __restrict__ W,
    ushort* __restrict__ Bp, int N, int NF, int idx) {
  int i = idx & 7;
  int lane = (idx >> 3) & 63;
  int rem = idx >> 9;
  int nf = rem % NF;
  int kf = rem / NF;
  int k = kf * 32 + (lane >> 4) * 8 + i;
  int col = nf * 16 + (lane & 15);
  float v = (col < N) ? W[(size_t)k * N + col] : 0.f;
  Bp[idx] = f2h(v);
}

__global__ __launch_bounds__(256) void k_setup(const int* __restrict__ dst,
    int* __restrict__ counts, const float* __restrict__ x, ushort* __restrict__ xb0,
    const float* __restrict__ W0, ushort* __restrict__ Bp0,
    const float* __restrict__ W1, ushort* __restrict__ Bp1,
    const float* __restrict__ W2, ushort* __restrict__ Bp2) {
  int gb = blockIdx.x;
  int tid = threadIdx.x;
  if (gb < 3072) {
    int stride = 3072 * 256;
    for (int i = gb * 256 + tid; i < TOT_E; i += stride) {
      int d = (i < NEDGES) ? dst[i] : (i - NEDGES);
      atomicAdd(&counts[d], 1);
    }
  } else if (gb < 5072) {
    int total4 = NODES * 128 / 4;
    int stride = 2000 * 256;
    for (int i = (gb - 3072) * 256 + tid; i < total4; i += stride) {
      float4 v = *(const float4*)&x[i * 4];
      ushort4 o;
      o.x = f2h(v.x); o.y = f2h(v.y); o.z = f2h(v.z); o.w = f2h(v.w);
      *(ushort4*)&xb0[i * 4] = o;
    }
  } else {
    int b = gb - 5072;
    int stride = 48 * 256;
    int base = b * 256 + tid;
    for (int idx = base; idx < 4 * 16 * 512; idx += stride) packB_one(W0, Bp0, 256, 16, idx);
    for (int idx = base; idx < 8 * 16 * 512; idx += stride) packB_one(W1, Bp1, 256, 16, idx);
    for (int idx = base; idx < 8 * 3 * 512; idx += stride)  packB_one(W2, Bp2, 40, 3, idx);
  }
}

// ---------------- CSR scan (red+part fused via last-block) + emit + scatter ----------------
__global__ __launch_bounds__(SCAN_B) void k_scan_red_part(const int* __restrict__ counts,
    int* __restrict__ bsum, int* __restrict__ bpre, int* __restrict__ done) {
  __shared__ int sm[SCAN_B];
  __shared__ int lastflag;
  int idx = blockIdx.x * SCAN_B + threadIdx.x;
  int v = (idx < NODES) ? counts[idx] : 0;
  sm[threadIdx.x] = v;
  __syncthreads();
  for (int off = SCAN_B / 2; off > 0; off >>= 1) {
    if (threadIdx.x < off) sm[threadIdx.x] += sm[threadIdx.x + off];
    __syncthreads();
  }
  if (threadIdx.x == 0) {
    __hip_atomic_store(&bsum[blockIdx.x], sm[0], __ATOMIC_RELEASE, __HIP_MEMORY_SCOPE_AGENT);
    int t = __hip_atomic_fetch_add(done, 1, __ATOMIC_ACQ_REL, __HIP_MEMORY_SCOPE_AGENT);
    lastflag = (t == (int)gridDim.x - 1);
  }
  __syncthreads();
  if (!lastflag) return;
  int tid = threadIdx.x;
  int b = (tid < SCAN_NB)
      ? __hip_atomic_load(&bsum[tid], __ATOMIC_ACQUIRE, __HIP_MEMORY_SCOPE_AGENT) : 0;
  __syncthreads();
  sm[tid] = b;
  __syncthreads();
  for (int off = 1; off < 256; off <<= 1) {
    int t2 = (tid >= off) ? sm[tid - off] : 0;
    __syncthreads();
    sm[tid] += t2;
    __syncthreads();
  }
  if (tid < SCAN_NB) bpre[tid] = sm[tid] - b;  // exclusive
}

__global__ __launch_bounds__(SCAN_B) void k_scan_emit(const int* __restrict__ counts,
    const int* __restrict__ bpre, int* __restrict__ offs, int* __restrict__ cur) {
  __shared__ int sm[SCAN_B];
  int idx = blockIdx.x * SCAN_B + threadIdx.x;
  int tid = threadIdx.x;
  int v = (idx < NODES) ? counts[idx] : 0;
  sm[tid] = v;
  __syncthreads();
  for (int off = 1; off < SCAN_B; off <<= 1) {
    int t = (tid >= off) ? sm[tid - off] : 0;
    __syncthreads();
    sm[tid] += t;
    __syncthreads();
  }
  int base = bpre[blockIdx.x];
  int excl = base + sm[tid] - v;
  if (idx < NODES) { offs[idx] = excl; cur[idx] = excl; }
  if (idx == NODES - 1) offs[NODES] = excl + v;
}

__global__ void k_scatter(const int* __restrict__ src, const int* __restrict__ dst,
                          int* __restrict__ cur, ushort* __restrict__ ssrc) {
  int stride = gridDim.x * blockDim.x;
  for (int i = blockIdx.x * blockDim.x + threadIdx.x; i < TOT_E; i += stride) {
    int s, d;
    if (i < NEDGES) { s = src[i]; d = dst[i]; } else { s = i - NEDGES; d = s; }
    int pos = atomicAdd(&cur[d], 1);
    ssrc[pos] = (ushort)s;
  }
}

// ---------------- register-resident-B MFMA GEMM (f16) + fused logits ----------------
template<int KF, int NFW, int CG, int HEADS, int NF_TOT>
__global__ __launch_bounds__(256, 2) void k_gemm_reg(
    const ushort* __restrict__ A, const ushort* __restrict__ Bp,
    ushort* __restrict__ H, const float* __restrict__ a_s, const float* __restrict__ a_d,
    float* __restrict__ al_s, float* __restrict__ al_d, int M, int N, int K) {
  int wib = threadIdx.x >> 6;
  int lane = threadIdx.x & 63;
  int lg = lane >> 4;
  int lr = lane & 15;
  int cg, strip0, sstride;
  if (CG == 4) { cg = wib; strip0 = blockIdx.x; sstride = gridDim.x; }
  else { cg = 0; strip0 = blockIdx.x * 4 + wib; sstride = gridDim.x * 4; }

  half8v b[KF][NFW];
#pragma unroll
  for (int kf = 0; kf < KF; ++kf)
#pragma unroll
    for (int n = 0; n < NFW; ++n)
      b[kf][n] = *(const half8v*)(Bp + ((size_t)(kf * NF_TOT + cg * NFW + n) * 64 + lane) * 8);

  float asc[NFW], adc[NFW];
#pragma unroll
  for (int n = 0; n < NFW; ++n) {
    int col = (cg * NFW + n) * 16 + lr;
    bool ok = col < N;
    asc[n] = ok ? a_s[col] : 0.f;
    adc[n] = ok ? a_d[col] : 0.f;
  }

  int nstrips = M >> 4;
  for (int strip = strip0; strip < nstrips; strip += sstride) {
    const ushort* arow = A + (size_t)(strip * 16 + lr) * K + lg * 8;
    half8v a[KF];
#pragma unroll
    for (int kf = 0; kf < KF; ++kf) a[kf] = *(const half8v*)(arow + kf * 32);
    f32x4 acc[NFW];
#pragma unroll
    for (int n = 0; n < NFW; ++n) acc[n] = (f32x4){0.f, 0.f, 0.f, 0.f};
#pragma unroll
    for (int kf = 0; kf < KF; ++kf)
#pragma unroll
      for (int n = 0; n < NFW; ++n)
        acc[n] = __builtin_amdgcn_mfma_f32_16x16x32_f16(a[kf], b[kf][n], acc[n], 0, 0, 0);

#pragma unroll
    for (int n = 0; n < NFW; ++n) {
      int col = (cg * NFW + n) * 16 + lr;
      if (col < N) {
#pragma unroll
        for (int r = 0; r < 4; ++r) {
          int row = strip * 16 + lg * 4 + r;
          H[(size_t)row * N + col] = f2h(acc[n][r]);
        }
      }
    }

    float ps[4], pd[4];
#pragma unroll
    for (int r = 0; r < 4; ++r) {
      float s = 0.f, d = 0.f;
#pragma unroll
      for (int n = 0; n < NFW; ++n) {
        s += acc[n][r] * asc[n];
        d += acc[n][r] * adc[n];
      }
      ps[r] = s; pd[r] = d;
    }
#pragma unroll
    for (int off = 1; off <= 8; off <<= 1)
#pragma unroll
      for (int t = 0; t < 4; ++t) {
        ps[t] += __shfl_xor(ps[t], off);
        pd[t] += __shfl_xor(pd[t], off);
      }
    if (lr < 4) {
      int row = strip * 16 + lg * 4 + lr;
      if (HEADS == 4) {
        al_s[row * 4 + cg] = ps[lr];
        al_d[row * 4 + cg] = pd[lr];
      } else {
        al_s[row] = ps[lr];
        al_d[row] = pd[lr];
      }
    }
  }
}

// ---------------- aggregation: head-pair split (r15 structure, 8 edges in flight) --
__global__ __launch_bounds__(256) void k_agg4(const ushort* __restrict__ hb,
    const float* __restrict__ al_s, const float* __restrict__ al_d,
    const int* __restrict__ offs, const ushort* __restrict__ ssrc,
    const float* __restrict__ bias, ushort* __restrict__ outb) {
  __shared__ uint s_sv[8][32];
  __shared__ uint s_al[8][2][33];
  int bid = blockIdx.x;
  int xcd = bid & 7;
  int hp = xcd >> 2;                      // channel half / head pair
  int nb = (bid >> 3) * 4 + (xcd & 3);    // node-block
  int hw = threadIdx.x >> 5;
  int node = nb * 8 + hw;
  if (node >= NODES) return;
  int l = threadIdx.x & 31;
  int beg = offs[node], end = offs[node + 1];
  float2 ald2 = *(const float2*)&al_d[node * 4 + hp * 2];

  // pass A: 2-head max
  float m0 = -1e30f, m1 = -1e30f;
  for (int i = beg + l; i < end; i += 32) {
    int sv = ssrc[i];
    float2 a2 = *(const float2*)&al_s[sv * 4 + hp * 2];
    m0 = fmaxf(m0, lrelu(a2.x + ald2.x));
    m1 = fmaxf(m1, lrelu(a2.y + ald2.y));
  }
#pragma unroll
  for (int off = 1; off <= 16; off <<= 1) {
    m0 = fmaxf(m0, __shfl_xor(m0, off));
    m1 = fmaxf(m1, __shfl_xor(m1, off));
  }

  int e = l >> 4;                 // edge parity
  int c = l & 15;                 // 16B group in half-row
  int hsel = c >> 3;              // head within pair
  uint clb = (uint)(hp * 128 + c * 8);
  float sacc0 = 0.f, sacc1 = 0.f;
  __half2 z2 = __float2half2_rn(0.f);
  __half2 accA[4] = {z2, z2, z2, z2};
  __half2 accB[4] = {z2, z2, z2, z2};

  for (int cb = beg; cb < end; cb += 32) {
    int cnt = min(32, end - cb);
    wave_lds_fence();
    if (l < cnt) {
      uint sv = (uint)ssrc[cb + l];
      float2 a2 = *(const float2*)&al_s[sv * 4 + hp * 2];
      float t0 = __expf(lrelu(a2.x + ald2.x) - m0);
      float t1 = __expf(lrelu(a2.y + ald2.y) - m1);
      sacc0 += t0; sacc1 += t1;
      U2H p0, p1;
      p0.h = __float2half2_rn(t0); p1.h = __float2half2_rn(t1);
      s_sv[hw][l] = sv;
      s_al[hw][0][l] = p0.u; s_al[hw][1][l] = p1.u;
    }
    wave_lds_fence();
    int ee = e;
    for (; ee + 14 < cnt; ee += 16) {   // 8 edges in flight per parity slot
      uint sv0 = s_sv[hw][ee],      sv1 = s_sv[hw][ee + 2];
      uint sv2 = s_sv[hw][ee + 4],  sv3 = s_sv[hw][ee + 6];
      uint sv4 = s_sv[hw][ee + 8],  sv5 = s_sv[hw][ee + 10];
      uint sv6 = s_sv[hw][ee + 12], sv7 = s_sv[hw][ee + 14];
      U2H a0, a1, a2, a3, a4, a5, a6, a7;
      a0.u = s_al[hw][hsel][ee];      a1.u = s_al[hw][hsel][ee + 2];
      a2.u = s_al[hw][hsel][ee + 4];  a3.u = s_al[hw][hsel][ee + 6];
      a4.u = s_al[hw][hsel][ee + 8];  a5.u = s_al[hw][hsel][ee + 10];
      a6.u = s_al[hw][hsel][ee + 12]; a7.u = s_al[hw][hsel][ee + 14];
      uint4 hv0 = *(const uint4*)(hb + ((sv0 << 8) + clb));
      uint4 hv1 = *(const uint4*)(hb + ((sv1 << 8) + clb));
      uint4 hv2 = *(const uint4*)(hb + ((sv2 << 8) + clb));
      uint4 hv3 = *(const uint4*)(hb + ((sv3 << 8) + clb));
      uint4 hv4 = *(const uint4*)(hb + ((sv4 << 8) + clb));
      uint4 hv5 = *(const uint4*)(hb + ((sv5 << 8) + clb));
      uint4 hv6 = *(const uint4*)(hb + ((sv6 << 8) + clb));
      uint4 hv7 = *(const uint4*)(hb + ((sv7 << 8) + clb));
      U2H v;
      v.u = hv0.x; accA[0] = __hfma2(a0.h, v.h, accA[0]);
      v.u = hv0.y; accA[1] = __hfma2(a0.h, v.h, accA[1]);
      v.u = hv0.z; accA[2] = __hfma2(a0.h, v.h, accA[2]);
      v.u = hv0.w; accA[3] = __hfma2(a0.h, v.h, accA[3]);
      v.u = hv1.x; accB[0] = __hfma2(a1.h, v.h, accB[0]);
      v.u = hv1.y; accB[1] = __hfma2(a1.h, v.h, accB[1]);
      v.u = hv1.z; accB[2] = __hfma2(a1.h, v.h, accB[2]);
      v.u = hv1.w; accB[3] = __hfma2(a1.h, v.h, accB[3]);
      v.u = hv2.x; accA[0] = __hfma2(a2.h, v.h, accA[0]);
      v.u = hv2.y; accA[1] = __hfma2(a2.h, v.h, accA[1]);
      v.u = hv2.z; accA[2] = __hfma2(a2.h, v.h, accA[2]);
      v.u = hv2.w; accA[3] = __hfma2(a2.h, v.h, accA[3]);
      v.u = hv3.x; accB[0] = __hfma2(a3.h, v.h, accB[0]);
      v.u = hv3.y; accB[1] = __hfma2(a3.h, v.h, accB[1]);
      v.u = hv3.z; accB[2] = __hfma2(a3.h, v.h, accB[2]);
      v.u = hv3.w; accB[3] = __hfma2(a3.h, v.h, accB[3]);
      v.u = hv4.x; accA[0] = __hfma2(a4.h, v.h, accA[0]);
      v.u = hv4.y; accA[1] = __hfma2(a4.h, v.h, accA[1]);
      v.u = hv4.z; accA[2] = __hfma2(a4.h, v.h, accA[2]);
      v.u = hv4.w; accA[3] = __hfma2(a4.h, v.h, accA[3]);
      v.u = hv5.x; accB[0] = __hfma2(a5.h, v.h, accB[0]);
      v.u = hv5.y; accB[1] = __hfma2(a5.h, v.h, accB[1]);
      v.u = hv5.z; accB[2] = __hfma2(a5.h, v.h, accB[2]);
      v.u = hv5.w; accB[3] = __hfma2(a5.h, v.h, accB[3]);
      v.u = hv6.x; accA[0] = __hfma2(a6.h, v.h, accA[0]);
      v.u = hv6.y; accA[1] = __hfma2(a6.h, v.h, accA[1]);
      v.u = hv6.z; accA[2] = __hfma2(a6.h, v.h, accA[2]);
      v.u = hv6.w; accA[3] = __hfma2(a6.h, v.h, accA[3]);
      v.u = hv7.x; accB[0] = __hfma2(a7.h, v.h, accB[0]);
      v.u = hv7.y; accB[1] = __hfma2(a7.h, v.h, accB[1]);
      v.u = hv7.z; accB[2] = __hfma2(a7.h, v.h, accB[2]);
      v.u = hv7.w; accB[3] = __hfma2(a7.h, v.h, accB[3]);
    }
    for (; ee + 6 < cnt; ee += 8) {   // 4 edges in flight
      uint sv0 = s_sv[hw][ee],     sv1 = s_sv[hw][ee + 2];
      uint sv2 = s_sv[hw][ee + 4], sv3 = s_sv[hw][ee + 6];
      U2H a0, a1, a2, a3;
      a0.u = s_al[hw][hsel][ee];     a1.u = s_al[hw][hsel][ee + 2];
      a2.u = s_al[hw][hsel][ee + 4]; a3.u = s_al[hw][hsel][ee + 6];
      uint4 hv0 = *(const uint4*)(hb + ((sv0 << 8) + clb));
      uint4 hv1 = *(const uint4*)(hb + ((sv1 << 8) + clb));
      uint4 hv2 = *(const uint4*)(hb + ((sv2 << 8) + clb));
      uint4 hv3 = *(const uint4*)(hb + ((sv3 << 8) + clb));
      U2H v;
      v.u = hv0.x; accA[0] = __hfma2(a0.h, v.h, accA[0]);
      v.u = hv0.y; accA[1] = __hfma2(a0.h, v.h, accA[1]);
      v.u = hv0.z; accA[2] = __hfma2(a0.h, v.h, accA[2]);
      v.u = hv0.w; accA[3] = __hfma2(a0.h, v.h, accA[3]);
      v.u = hv1.x; accB[0] = __hfma2(a1.h, v.h, accB[0]);
      v.u = hv1.y; accB[1] = __hfma2(a1.h, v.h, accB[1]);
      v.u = hv1.z; accB[2] = __hfma2(a1.h, v.h, accB[2]);
      v.u = hv1.w; accB[3] = __hfma2(a1.h, v.h, accB[3]);
      v.u = hv2.x; accA[0] = __hfma2(a2.h, v.h, accA[0]);
      v.u = hv2.y; accA[1] = __hfma2(a2.h, v.h, accA[1]);
      v.u = hv2.z; accA[2] = __hfma2(a2.h, v.h, accA[2]);
      v.u = hv2.w; accA[3] = __hfma2(a2.h, v.h, accA[3]);
      v.u = hv3.x; accB[0] = __hfma2(a3.h, v.h, accB[0]);
      v.u = hv3.y; accB[1] = __hfma2(a3.h, v.h, accB[1]);
      v.u = hv3.z; accB[2] = __hfma2(a3.h, v.h, accB[2]);
      v.u = hv3.w; accB[3] = __hfma2(a3.h, v.h, accB[3]);
    }
    for (; ee < cnt; ee += 2) {
      uint sv = s_sv[hw][ee];
      U2H a0; a0.u = s_al[hw][hsel][ee];
      uint4 hv = *(const uint4*)(hb + ((sv << 8) + clb));
      U2H v;
      v.u = hv.x; accA[0] = __hfma2(a0.h, v.h, accA[0]);
      v.u = hv.y; accA[1] = __hfma2(a0.h, v.h, accA[1]);
      v.u = hv.z; accA[2] = __hfma2(a0.h, v.h, accA[2]);
      v.u = hv.w; accA[3] = __hfma2(a0.h, v.h, accA[3]);
    }
  }
#pragma unroll
  for (int off = 1; off <= 16; off <<= 1) {
    sacc0 += __shfl_xor(sacc0, off);
    sacc1 += __shfl_xor(sacc1, off);
  }
  float invs = 1.f / (hsel ? sacc1 : sacc0);
  ushort4 ores[2];
#pragma unroll
  for (int j = 0; j < 4; ++j) {
    U2H t; t.h = __hadd2(accA[j], accB[j]);
    U2H o; o.u = __shfl_xor(t.u, 16);
    t.h = __hadd2(t.h, o.h);
    float lo = __low2float(t.h) * invs + bias[clb + j * 2];
    float hi = __high2float(t.h) * invs + bias[clb + j * 2 + 1];
    lo = lo > 0.f ? lo : __expf(lo) - 1.f;
    hi = hi > 0.f ? hi : __expf(hi) - 1.f;
    ((ushort*)ores)[j * 2]     = f2h(lo);
    ((ushort*)ores)[j * 2 + 1] = f2h(hi);
  }
  if (e == 0) {
    *(ushort4*)(outb + (size_t)node * 256 + clb)     = ores[0];
    *(ushort4*)(outb + (size_t)node * 256 + clb + 4) = ores[1];
  }
}

// layer 2: H=1, C=40, f16; half-wave per node, 8 edges in flight
__global__ __launch_bounds__(256) void k_agg1(const ushort* __restrict__ hb,
    const float* __restrict__ al_s, const float* __restrict__ al_d,
    const int* __restrict__ offs, const ushort* __restrict__ ssrc,
    const float* __restrict__ bias, float* __restrict__ out) {
  __shared__ uint s_sv[8][32];
  __shared__ uint s_al[8][32];
  int hw = threadIdx.x >> 5;
  int node = (blockIdx.x * 256 + threadIdx.x) >> 5;
  if (node >= NODES) return;
  int l = threadIdx.x & 31;
  int beg = offs[node], end = offs[node + 1];
  float ald = al_d[node];

  float m = -1e30f;
  for (int i = beg + l; i < end; i += 32)
    m = fmaxf(m, lrelu(al_s[ssrc[i]] + ald));
#pragma unroll
  for (int off = 1; off <= 16; off <<= 1) m = fmaxf(m, __shfl_xor(m, off));

  int p = l >> 4;
  int cq = l & 15;
  bool act = cq < 10;
  uint cqb = (uint)cq * 4;
  float sacc = 0.f;
  __half2 z2 = __float2half2_rn(0.f);
  __half2 accA[2] = {z2, z2};
  __half2 accB[2] = {z2, z2};
  for (int cb = beg; cb < end; cb += 32) {
    int cnt = min(32, end - cb);
    wave_lds_fence();
    if (l < cnt) {
      uint sv = (uint)ssrc[cb + l];
      float t = __expf(lrelu(al_s[sv] + ald) - m);
      sacc += t;
      U2H pk; pk.h = __float2half2_rn(t);
      s_sv[hw][l] = sv;
      s_al[hw][l] = pk.u;
    }
    wave_lds_fence();
    int e = p;
    for (; e + 14 < cnt; e += 16) {
      uint sv0 = s_sv[hw][e],      sv1 = s_sv[hw][e + 2];
      uint sv2 = s_sv[hw][e + 4],  sv3 = s_sv[hw][e + 6];
      uint sv4 = s_sv[hw][e + 8],  sv5 = s_sv[hw][e + 10];
      uint sv6 = s_sv[hw][e + 12], sv7 = s_sv[hw][e + 14];
      U2H a0, a1, a2, a3, a4, a5, a6, a7;
      a0.u = s_al[hw][e];      a1.u = s_al[hw][e + 2];
      a2.u = s_al[hw][e + 4];  a3.u = s_al[hw][e + 6];
      a4.u = s_al[hw][e + 8];  a5.u = s_al[hw][e + 10];
      a6.u = s_al[hw][e + 12]; a7.u = s_al[hw][e + 14];
      if (act) {
        uint2 hv0 = *(const uint2*)(hb + (sv0 * 40u + cqb));
        uint2 hv1 = *(const uint2*)(hb + (sv1 * 40u + cqb));
        uint2 hv2 = *(const uint2*)(hb + (sv2 * 40u + cqb));
        uint2 hv3 = *(const uint2*)(hb + (sv3 * 40u + cqb));
        uint2 hv4 = *(const uint2*)(hb + (sv4 * 40u + cqb));
        uint2 hv5 = *(const uint2*)(hb + (sv5 * 40u + cqb));
        uint2 hv6 = *(const uint2*)(hb + (sv6 * 40u + cqb));
        uint2 hv7 = *(const uint2*)(hb + (sv7 * 40u + cqb));
        U2H v;
        v.u = hv0.x; accA[0] = __hfma2(a0.h, v.h, accA[0]);
        v.u = hv0.y; accA[1] = __hfma2(a0.h, v.h, accA[1]);
        v.u = hv1.x; accB[0] = __hfma2(a1.h, v.h, accB[0]);
        v.u = hv1.y; accB[1] = __hfma2(a1.h, v.h, accB[1]);
        v.u = hv2.x; accA[0] = __hfma2(a2.h, v.h, accA[0]);
        v.u = hv2.y; accA[1] = __hfma2(a2.h, v.h, accA[1]);
        v.u = hv3.x; accB[0] = __hfma2(a3.h, v.h, accB[0]);
        v.u = hv3.y; accB[1] = __hfma2(a3.h, v.h, accB[1]);
        v.u = hv4.x; accA[0] = __hfma2(a4.h, v.h, accA[0]);
        v.u = hv4.y; accA[1] = __hfma2(a4.h, v.h, accA[1]);
        v.u = hv5.x; accB[0] = __hfma2(a5.h, v.h, accB[0]);
        v.u = hv5.y; accB[1] = __hfma2(a5.h, v.h, accB[1]);
        v.u = hv6.x; accA[0] = __hfma2(a6.h, v.h, accA[0]);
        v.u = hv6.y; accA[1] = __hfma2(a6.h, v.h, accA[1]);
        v.u = hv7.x; accB[0] = __hfma2(a7.h, v.h, accB[0]);
        v.u = hv7.y; accB[1] = __hfma2(a7.h, v.h, accB[1]);
      }
    }
    for (; e + 6 < cnt; e += 8) {
      uint sv0 = s_sv[hw][e],     sv1 = s_sv[hw][e + 2];
      uint sv2 = s_sv[hw][e + 4], sv3 = s_sv[hw][e + 6];
      U2H a0, a1, a2, a3;
      a0.u = s_al[hw][e];     a1.u = s_al[hw][e + 2];
      a2.u = s_al[hw][e + 4]; a3.u = s_al[hw][e + 6];
      if (act) {
        uint2 hv0 = *(const uint2*)(hb + (sv0 * 40u + cqb));
        uint2 hv1 = *(const uint2*)(hb + (sv1 * 40u + cqb));
        uint2 hv2 = *(const uint2*)(hb + (sv2 * 40u + cqb));
        uint2 hv3 = *(const uint2*)(hb + (sv3 * 40u + cqb));
        U2H v;
        v.u = hv0.x; accA[0] = __hfma2(a0.h, v.h, accA[0]);
        v.u = hv0.y; accA[1] = __hfma2(a0.h, v.h, accA[1]);
        v.u = hv1.x; accB[0] = __hfma2(a1.h, v.h, accB[0]);
        v.u = hv1.y; accB[1] = __hfma2(a1.h, v.h, accB[1]);
        v.u = hv2.x; accA[0] = __hfma2(a2.h, v.h, accA[0]);
        v.u = hv2.y; accA[1] = __hfma2(a2.h, v.h, accA[1]);
        v.u = hv3.x; accB[0] = __hfma2(a3.h, v.h, accB[0]);
        v.u = hv3.y; accB[1] = __hfma2(a3.h, v.h, accB[1]);
      }
    }
    for (; e < cnt; e += 2) {
      uint sv = s_sv[hw][e];
      U2H a0; a0.u = s_al[hw][e];
      if (act) {
        uint2 hv = *(const uint2*)(hb + (sv * 40u + cqb));
        U2H v;
        v.u = hv.x; accA[0] = __hfma2(a0.h, v.h, accA[0]);
        v.u = hv.y; accA[1] = __hfma2(a0.h, v.h, accA[1]);
      }
    }
  }
#pragma unroll
  for (int off = 1; off <= 16; off <<= 1) sacc += __shfl_xor(sacc, off);
  float invs = 1.f / sacc;
  float vv[4];
#pragma unroll
  for (int j = 0; j < 2; ++j) {
    U2H t; t.h = __hadd2(accA[j], accB[j]);
    U2H o; o.u = __shfl_xor(t.u, 16);
    t.h = __hadd2(t.h, o.h);
    vv[j * 2]     = __low2float(t.h) * invs;
    vv[j * 2 + 1] = __high2float(t.h) * invs;
  }
  float mm = -1e30f;
  if (act) {
#pragma unroll
    for (int j = 0; j < 4; ++j) {
      vv[j] += bias[cq * 4 + j];
      mm = fmaxf(mm, vv[j]);
    }
  }
#pragma unroll
  for (int off = 1; off <= 8; off <<= 1) mm = fmaxf(mm, __shfl_xor(mm, off));
  float se = 0.f;
  if (act) {
#pragma unroll
    for (int j = 0; j < 4; ++j) se += __expf(vv[j] - mm);
  }
#pragma unroll
  for (int off = 1; off <= 8; off <<= 1) se += __shfl_xor(se, off);
  if (act && p == 0) {
    float lse = mm + __logf(se);
    float4 o;
    o.x = vv[0] - lse; o.y = vv[1] - lse; o.z = vv[2] - lse; o.w = vv[3] - lse;
    *(float4*)&out[(size_t)node * 40 + cq * 4] = o;
  }
}

// ---------------- launch ----------------
extern "C" void kernel_launch(void* const* d_in, const int* in_sizes, int n_in,
                              void* d_out, int out_size, void* d_ws, size_t ws_size,
                              hipStream_t stream) {
  const float* x   = (const float*)d_in[0];
  const int*   ei  = (const int*)d_in[1];
  const float* W0  = (const float*)d_in[2];
  const float* as0 = (const float*)d_in[3];
  const float* ad0 = (const float*)d_in[4];
  const float* b0  = (const float*)d_in[5];
  const float* W1  = (const float*)d_in[6];
  const float* as1 = (const float*)d_in[7];
  const float* ad1 = (const float*)d_in[8];
  const float* b1  = (const float*)d_in[9];
  const float* W2  = (const float*)d_in[10];
  const float* as2 = (const float*)d_in[11];
  const float* ad2 = (const float*)d_in[12];
  const float* b2  = (const float*)d_in[13];
  float* out = (float*)d_out;

  char* p = (char*)d_ws;
  auto take = [&](size_t bytes) {
    char* q = p;
    p += (bytes + 255) & ~(size_t)255;
    return (void*)q;
  };
  ushort* xb0 = (ushort*)take((size_t)NODES * 128 * 2);
  ushort* xb1 = (ushort*)take((size_t)NODES * 256 * 2);
  ushort* xb2 = (ushort*)take((size_t)NODES * 256 * 2);
  ushort* hb  = (ushort*)take((size_t)NODES * 256 * 2);
  float* als  = (float*)take((size_t)NODES * 4 * 4);
  float* ald  = (float*)take((size_t)NODES * 4 * 4);
  ushort* ssrc= (ushort*)take((size_t)TOT_E * 2);
  int* offs   = (int*)take((size_t)(NODES + 1) * 4);
  int* cur    = (int*)take((size_t)NODES * 4);
  int* cnt    = (int*)take((size_t)(NODES + 64) * 4);
  int* done   = cnt + NODES;
  int* bsum   = (int*)take((size_t)SCAN_NB * 4);
  int* bpre   = (int*)take((size_t)SCAN_NB * 4);
  ushort* Bp0 = (ushort*)take((size_t)4 * 16 * 512 * 2);
  ushort* Bp1 = (ushort*)take((size_t)8 * 16 * 512 * 2);
  ushort* Bp2 = (ushort*)take((size_t)8 * 3 * 512 * 2);

  hipMemsetAsync(cnt, 0, (size_t)(NODES + 64) * 4, stream);
  k_setup<<<5120, 256, 0, stream>>>(ei + NEDGES, cnt, x, xb0, W0, Bp0, W1, Bp1, W2, Bp2);
  k_scan_red_part<<<SCAN_NB, SCAN_B, 0, stream>>>(cnt, bsum, bpre, done);
  k_scan_emit<<<SCAN_NB, SCAN_B, 0, stream>>>(cnt, bpre, offs, cur);
  k_scatter<<<4096, 256, 0, stream>>>(ei, ei + NEDGES, cur, ssrc);

  int nab = (NODES * 32 + 255) / 256;            // 6250 node-blocks (8 nodes each)
  int nab4 = (nab + 3) & ~3;                     // round to 4 for the 8-way mapping
  int nagg4 = nab4 * 2;                          // x2 channel halves

  // layer 0
  k_gemm_reg<4, 4, 4, 4, 16><<<512, 256, 0, stream>>>(xb0, Bp0, hb, as0, ad0, als, ald, NODES, 256, 128);
  k_agg4<<<nagg4, 256, 0, stream>>>(hb, als, ald, offs, ssrc, b0, xb1);

  // layer 1
  k_gemm_reg<8, 4, 4, 4, 16><<<512, 256, 0, stream>>>(xb1, Bp1, hb, as1, ad1, als, ald, NODES, 256, 256);
  k_agg4<<<nagg4, 256, 0, stream>>>(hb, als, ald, offs, ssrc, b1, xb2);

  // layer 2
  k_gemm_reg<8, 3, 1, 1, 3><<<512, 256, 0, stream>>>(xb2, Bp2, hb, as2, ad2, als, ald, NODES, 40, 256);
  k_agg1<<<nab, 256, 0, stream>>>(hb, als, ald, offs, ssrc, b2, out);
}

// Round 18
// 287.554 us; speedup vs baseline: 1.1196x; 1.0286x over previous
//
#include <hip/hip_runtime.h>
#include <hip/hip_fp16.h>
#include <math.h>

#define NODES 50000
#define NEDGES 800000
#define TOT_E (NEDGES + NODES)
#define SCAN_B 256
#define SCAN_NB ((NODES + SCAN_B - 1) / SCAN_B)

typedef __attribute__((ext_vector_type(8))) _Float16 half8v;
typedef __attribute__((ext_vector_type(4))) float f32x4;

union U2H { uint u; __half2 h; };

static __device__ __forceinline__ float lrelu(float z) {
  return z > 0.f ? z : 0.2f * z;
}
static __device__ __forceinline__ ushort f2h(float f) {
  __half h = __float2half_rn(f);
  return *reinterpret_cast<ushort*>(&h);
}
static __device__ __forceinline__ void wave_lds_fence() {
  __builtin_amdgcn_wave_barrier();
  asm volatile("s_waitcnt lgkmcnt(0)" ::: "memory");
  __builtin_amdgcn_sched_barrier(0);
}

// ---------------- fused setup: hist + cast + packB x3 ----------------
static __device__ __forceinline__ void packB_one(const float* __restrict__ W,
    ushort* __restrict__ Bp, int N, int NF, int idx) {
  int i = idx & 7;
  int lane = (idx >> 3) & 63;
  int rem = idx >> 9;
  int nf = rem % NF;
  int kf = rem / NF;
  int k = kf * 32 + (lane >> 4) * 8 + i;
  int col = nf * 16 + (lane & 15);
  float v = (col < N) ? W[(size_t)k * N + col] : 0.f;
  Bp[idx] = f2h(v);
}

__global__ __launch_bounds__(256) void k_setup(const int* __restrict__ dst,
    int* __restrict__ counts, const float* __restrict__ x, ushort* __restrict__ xb0,
    const float* __restrict__ W0, ushort* __restrict__ Bp0,
    const float* __restrict__ W1, ushort* __restrict__ Bp1,
    const float* __restrict__ W2, ushort* __restrict__ Bp2) {
  int gb = blockIdx.x;
  int tid = threadIdx.x;
  if (gb < 2048) {
    int stride = 2048 * 256;
    for (int i = gb * 256 + tid; i < TOT_E; i += stride) {
      int d = (i < NEDGES) ? dst[i] : (i - NEDGES);
      atomicAdd(&counts[d], 1);
    }
  } else if (gb < 4048) {
    int total4 = NODES * 128 / 4;
    int stride = 2000 * 256;
    for (int i = (gb - 2048) * 256 + tid; i < total4; i += stride) {
      float4 v = *(const float4*)&x[i * 4];
      ushort4 o;
      o.x = f2h(v.x); o.y = f2h(v.y); o.z = f2h(v.z); o.w = f2h(v.w);
      *(ushort4*)&xb0[i * 4] = o;
    }
  } else {
    int b = gb - 4048;
    int stride = 48 * 256;
    int base = b * 256 + tid;
    for (int idx = base; idx < 4 * 16 * 512; idx += stride) packB_one(W0, Bp0, 256, 16, idx);
    for (int idx = base; idx < 8 * 16 * 512; idx += stride) packB_one(W1, Bp1, 256, 16, idx);
    for (int idx = base; idx < 8 * 3 * 512; idx += stride)  packB_one(W2, Bp2, 40, 3, idx);
  }
}

// ---------------- CSR scan (red+part fused via last-block) + emit + scatter ----------------
__global__ __launch_bounds__(SCAN_B) void k_scan_red_part(const int* __restrict__ counts,
    int* __restrict__ bsum, int* __restrict__ bpre, int* __restrict__ done) {
  __shared__ int sm[SCAN_B];
  __shared__ int lastflag;
  int idx = blockIdx.x * SCAN_B + threadIdx.x;
  int v = (idx < NODES) ? counts[idx] : 0;
  sm[threadIdx.x] = v;
  __syncthreads();
  for (int off = SCAN_B / 2; off > 0; off >>= 1) {
    if (threadIdx.x < off) sm[threadIdx.x] += sm[threadIdx.x + off];
    __syncthreads();
  }
  if (threadIdx.x == 0) {
    __hip_atomic_store(&bsum[blockIdx.x], sm[0], __ATOMIC_RELEASE, __HIP_MEMORY_SCOPE_AGENT);
    int t = __hip_atomic_fetch_add(done, 1, __ATOMIC_ACQ_REL, __HIP_MEMORY_SCOPE_AGENT);
    lastflag = (t == (int)gridDim.x - 1);
  }
  __syncthreads();
  if (!lastflag) return;
  int tid = threadIdx.x;
  int b = (tid < SCAN_NB)
      ? __hip_atomic_load(&bsum[tid], __ATOMIC_ACQUIRE, __HIP_MEMORY_SCOPE_AGENT) : 0;
  __syncthreads();
  sm[tid] = b;
  __syncthreads();
  for (int off = 1; off < 256; off <<= 1) {
    int t2 = (tid >= off) ? sm[tid - off] : 0;
    __syncthreads();
    sm[tid] += t2;
    __syncthreads();
  }
  if (tid < SCAN_NB) bpre[tid] = sm[tid] - b;  // exclusive
}

__global__ __launch_bounds__(SCAN_B) void k_scan_emit(const int* __restrict__ counts,
    const int* __restrict__ bpre, int* __restrict__ offs, int* __restrict__ cur) {
  __shared__ int sm[SCAN_B];
  int idx = blockIdx.x * SCAN_B + threadIdx.x;
  int tid = threadIdx.x;
  int v = (idx < NODES) ? counts[idx] : 0;
  sm[tid] = v;
  __syncthreads();
  for (int off = 1; off < SCAN_B; off <<= 1) {
    int t = (tid >= off) ? sm[tid - off] : 0;
    __syncthreads();
    sm[tid] += t;
    __syncthreads();
  }
  int base = bpre[blockIdx.x];
  int excl = base + sm[tid] - v;
  if (idx < NODES) { offs[idx] = excl; cur[idx] = excl; }
  if (idx == NODES - 1) offs[NODES] = excl + v;
}

__global__ void k_scatter(const int* __restrict__ src, const int* __restrict__ dst,
                          int* __restrict__ cur, ushort* __restrict__ ssrc) {
  int stride = gridDim.x * blockDim.x;
  for (int i = blockIdx.x * blockDim.x + threadIdx.x; i < TOT_E; i += stride) {
    int s, d;
    if (i < NEDGES) { s = src[i]; d = dst[i]; } else { s = i - NEDGES; d = s; }
    int pos = atomicAdd(&cur[d], 1);
    ssrc[pos] = (ushort)s;
  }
}

// ---------------- register-resident-B MFMA GEMM (f16) + fused logits ----------------
template<int KF, int NFW, int CG, int HEADS, int NF_TOT>
__global__ __launch_bounds__(256, 2) void k_gemm_reg(
    const ushort* __restrict__ A, const ushort* __restrict__ Bp,
    ushort* __restrict__ H, const float* __restrict__ a_s, const float* __restrict__ a_d,
    float* __restrict__ al_s, float* __restrict__ al_d, int M, int N, int K) {
  int wib = threadIdx.x >> 6;
  int lane = threadIdx.x & 63;
  int lg = lane >> 4;
  int lr = lane & 15;
  int cg, strip0, sstride;
  if (CG == 4) { cg = wib; strip0 = blockIdx.x; sstride = gridDim.x; }
  else { cg = 0; strip0 = blockIdx.x * 4 + wib; sstride = gridDim.x * 4; }

  half8v b[KF][NFW];
#pragma unroll
  for (int kf = 0; kf < KF; ++kf)
#pragma unroll
    for (int n = 0; n < NFW; ++n)
      b[kf][n] = *(const half8v*)(Bp + ((size_t)(kf * NF_TOT + cg * NFW + n) * 64 + lane) * 8);

  float asc[NFW], adc[NFW];
#pragma unroll
  for (int n = 0; n < NFW; ++n) {
    int col = (cg * NFW + n) * 16 + lr;
    bool ok = col < N;
    asc[n] = ok ? a_s[col] : 0.f;
    adc[n] = ok ? a_d[col] : 0.f;
  }

  int nstrips = M >> 4;
  for (int strip = strip0; strip < nstrips; strip += sstride) {
    const ushort* arow = A + (size_t)(strip * 16 + lr) * K + lg * 8;
    half8v a[KF];
#pragma unroll
    for (int kf = 0; kf < KF; ++kf) a[kf] = *(const half8v*)(arow + kf * 32);
    f32x4 acc[NFW];
#pragma unroll
    for (int n = 0; n < NFW; ++n) acc[n] = (f32x4){0.f, 0.f, 0.f, 0.f};
#pragma unroll
    for (int kf = 0; kf < KF; ++kf)
#pragma unroll
      for (int n = 0; n < NFW; ++n)
        acc[n] = __builtin_amdgcn_mfma_f32_16x16x32_f16(a[kf], b[kf][n], acc[n], 0, 0, 0);

#pragma unroll
    for (int n = 0; n < NFW; ++n) {
      int col = (cg * NFW + n) * 16 + lr;
      if (col < N) {
#pragma unroll
        for (int r = 0; r < 4; ++r) {
          int row = strip * 16 + lg * 4 + r;
          H[(size_t)row * N + col] = f2h(acc[n][r]);
        }
      }
    }

    float ps[4], pd[4];
#pragma unroll
    for (int r = 0; r < 4; ++r) {
      float s = 0.f, d = 0.f;
#pragma unroll
      for (int n = 0; n < NFW; ++n) {
        s += acc[n][r] * asc[n];
        d += acc[n][r] * adc[n];
      }
      ps[r] = s; pd[r] = d;
    }
#pragma unroll
    for (int off = 1; off <= 8; off <<= 1)
#pragma unroll
      for (int t = 0; t < 4; ++t) {
        ps[t] += __shfl_xor(ps[t], off);
        pd[t] += __shfl_xor(pd[t], off);
      }
    if (lr < 4) {
      int row = strip * 16 + lg * 4 + lr;
      if (HEADS == 4) {
        al_s[row * 4 + cg] = ps[lr];
        al_d[row * 4 + cg] = pd[lr];
      } else {
        al_s[row] = ps[lr];
        al_d[row] = pd[lr];
      }
    }
  }
}

// ---------------- aggregation: head-pair split, half-wave per (node, half) ----------
// Channel half hp = (blockIdx&7)>>2 -> XCDs 0-3 serve channels [0,128) (heads 0,1),
// XCDs 4-7 serve [128,256) (heads 2,3): per-XCD gather footprint 12.8MB.
// 32 lanes: e = l>>4 edge parity, c = l&15 -> 16B of the 256B half-row.
__global__ __launch_bounds__(256) void k_agg4(const ushort* __restrict__ hb,
    const float* __restrict__ al_s, const float* __restrict__ al_d,
    const int* __restrict__ offs, const ushort* __restrict__ ssrc,
    const float* __restrict__ bias, ushort* __restrict__ outb) {
  __shared__ uint s_sv[8][32];
  __shared__ uint s_al[8][2][33];
  int bid = blockIdx.x;
  int xcd = bid & 7;
  int hp = xcd >> 2;                      // channel half / head pair
  int nb = (bid >> 3) * 4 + (xcd & 3);    // node-block
  int hw = threadIdx.x >> 5;
  int node = nb * 8 + hw;
  if (node >= NODES) return;
  int l = threadIdx.x & 31;
  int beg = offs[node], end = offs[node + 1];
  float2 ald2 = *(const float2*)&al_d[node * 4 + hp * 2];

  // pass A: 2-head max
  float m0 = -1e30f, m1 = -1e30f;
  for (int i = beg + l; i < end; i += 32) {
    int sv = ssrc[i];
    float2 a2 = *(const float2*)&al_s[sv * 4 + hp * 2];
    m0 = fmaxf(m0, lrelu(a2.x + ald2.x));
    m1 = fmaxf(m1, lrelu(a2.y + ald2.y));
  }
#pragma unroll
  for (int off = 1; off <= 16; off <<= 1) {
    m0 = fmaxf(m0, __shfl_xor(m0, off));
    m1 = fmaxf(m1, __shfl_xor(m1, off));
  }

  int e = l >> 4;                 // edge parity
  int c = l & 15;                 // 16B group in half-row
  int hsel = c >> 3;              // head within pair for these channels
  uint clb = (uint)(hp * 128 + c * 8);   // element offset in full row
  float sacc0 = 0.f, sacc1 = 0.f;
  __half2 z2 = __float2half2_rn(0.f);
  __half2 accA[4] = {z2, z2, z2, z2};
  __half2 accB[4] = {z2, z2, z2, z2};

  for (int cb = beg; cb < end; cb += 32) {
    int cnt = min(32, end - cb);
    wave_lds_fence();
    if (l < cnt) {
      uint sv = (uint)ssrc[cb + l];
      float2 a2 = *(const float2*)&al_s[sv * 4 + hp * 2];
      float t0 = __expf(lrelu(a2.x + ald2.x) - m0);
      float t1 = __expf(lrelu(a2.y + ald2.y) - m1);
      sacc0 += t0; sacc1 += t1;
      U2H p0, p1;
      p0.h = __float2half2_rn(t0); p1.h = __float2half2_rn(t1);
      s_sv[hw][l] = sv;
      s_al[hw][0][l] = p0.u; s_al[hw][1][l] = p1.u;
    }
    wave_lds_fence();
    int ee = e;
    for (; ee + 6 < cnt; ee += 8) {   // 4 edges in flight per parity slot
      uint sv0 = s_sv[hw][ee],     sv1 = s_sv[hw][ee + 2];
      uint sv2 = s_sv[hw][ee + 4], sv3 = s_sv[hw][ee + 6];
      U2H a0, a1, a2, a3;
      a0.u = s_al[hw][hsel][ee];     a1.u = s_al[hw][hsel][ee + 2];
      a2.u = s_al[hw][hsel][ee + 4]; a3.u = s_al[hw][hsel][ee + 6];
      uint4 hv0 = *(const uint4*)(hb + ((sv0 << 8) + clb));
      uint4 hv1 = *(const uint4*)(hb + ((sv1 << 8) + clb));
      uint4 hv2 = *(const uint4*)(hb + ((sv2 << 8) + clb));
      uint4 hv3 = *(const uint4*)(hb + ((sv3 << 8) + clb));
      U2H v;
      v.u = hv0.x; accA[0] = __hfma2(a0.h, v.h, accA[0]);
      v.u = hv0.y; accA[1] = __hfma2(a0.h, v.h, accA[1]);
      v.u = hv0.z; accA[2] = __hfma2(a0.h, v.h, accA[2]);
      v.u = hv0.w; accA[3] = __hfma2(a0.h, v.h, accA[3]);
      v.u = hv1.x; accB[0] = __hfma2(a1.h, v.h, accB[0]);
      v.u = hv1.y; accB[1] = __hfma2(a1.h, v.h, accB[1]);
      v.u = hv1.z; accB[2] = __hfma2(a1.h, v.h, accB[2]);
      v.u = hv1.w; accB[3] = __hfma2(a1.h, v.h, accB[3]);
      v.u = hv2.x; accA[0] = __hfma2(a2.h, v.h, accA[0]);
      v.u = hv2.y; accA[1] = __hfma2(a2.h, v.h, accA[1]);
      v.u = hv2.z; accA[2] = __hfma2(a2.h, v.h, accA[2]);
      v.u = hv2.w; accA[3] = __hfma2(a2.h, v.h, accA[3]);
      v.u = hv3.x; accB[0] = __hfma2(a3.h, v.h, accB[0]);
      v.u = hv3.y; accB[1] = __hfma2(a3.h, v.h, accB[1]);
      v.u = hv3.z; accB[2] = __hfma2(a3.h, v.h, accB[2]);
      v.u = hv3.w; accB[3] = __hfma2(a3.h, v.h, accB[3]);
    }
    for (; ee < cnt; ee += 2) {
      uint sv = s_sv[hw][ee];
      U2H a0; a0.u = s_al[hw][hsel][ee];
      uint4 hv = *(const uint4*)(hb + ((sv << 8) + clb));
      U2H v;
      v.u = hv.x; accA[0] = __hfma2(a0.h, v.h, accA[0]);
      v.u = hv.y; accA[1] = __hfma2(a0.h, v.h, accA[1]);
      v.u = hv.z; accA[2] = __hfma2(a0.h, v.h, accA[2]);
      v.u = hv.w; accA[3] = __hfma2(a0.h, v.h, accA[3]);
    }
  }
#pragma unroll
  for (int off = 1; off <= 16; off <<= 1) {
    sacc0 += __shfl_xor(sacc0, off);
    sacc1 += __shfl_xor(sacc1, off);
  }
  float invs = 1.f / (hsel ? sacc1 : sacc0);
  // merge edge parities, normalize + bias + ELU, write 16B
  ushort4 ores[2];
#pragma unroll
  for (int j = 0; j < 4; ++j) {
    U2H t; t.h = __hadd2(accA[j], accB[j]);
    U2H o; o.u = __shfl_xor(t.u, 16);
    t.h = __hadd2(t.h, o.h);
    float lo = __low2float(t.h) * invs + bias[clb + j * 2];
    float hi = __high2float(t.h) * invs + bias[clb + j * 2 + 1];
    lo = lo > 0.f ? lo : __expf(lo) - 1.f;
    hi = hi > 0.f ? hi : __expf(hi) - 1.f;
    ((ushort*)ores)[j * 2]     = f2h(lo);
    ((ushort*)ores)[j * 2 + 1] = f2h(hi);
  }
  if (e == 0) {
    *(ushort4*)(outb + (size_t)node * 256 + clb)     = ores[0];
    *(ushort4*)(outb + (size_t)node * 256 + clb + 4) = ores[1];
  }
}

// layer 2: H=1, C=40, f16; half-wave per node, 8 edges in flight
__global__ __launch_bounds__(256) void k_agg1(const ushort* __restrict__ hb,
    const float* __restrict__ al_s, const float* __restrict__ al_d,
    const int* __restrict__ offs, const ushort* __restrict__ ssrc,
    const float* __restrict__ bias, float* __restrict__ out) {
  __shared__ uint s_sv[8][32];
  __shared__ uint s_al[8][32];
  int hw = threadIdx.x >> 5;
  int node = (blockIdx.x * 256 + threadIdx.x) >> 5;
  if (node >= NODES) return;
  int l = threadIdx.x & 31;
  int beg = offs[node], end = offs[node + 1];
  float ald = al_d[node];

  float m = -1e30f;
  for (int i = beg + l; i < end; i += 32)
    m = fmaxf(m, lrelu(al_s[ssrc[i]] + ald));
#pragma unroll
  for (int off = 1; off <= 16; off <<= 1) m = fmaxf(m, __shfl_xor(m, off));

  int p = l >> 4;
  int cq = l & 15;
  bool act = cq < 10;
  uint cqb = (uint)cq * 4;
  float sacc = 0.f;
  __half2 z2 = __float2half2_rn(0.f);
  __half2 accA[2] = {z2, z2};
  __half2 accB[2] = {z2, z2};
  for (int cb = beg; cb < end; cb += 32) {
    int cnt = min(32, end - cb);
    wave_lds_fence();
    if (l < cnt) {
      uint sv = (uint)ssrc[cb + l];
      float t = __expf(lrelu(al_s[sv] + ald) - m);
      sacc += t;
      U2H pk; pk.h = __float2half2_rn(t);
      s_sv[hw][l] = sv;
      s_al[hw][l] = pk.u;
    }
    wave_lds_fence();
    int e = p;
    for (; e + 14 < cnt; e += 16) {
      uint sv0 = s_sv[hw][e],      sv1 = s_sv[hw][e + 2];
      uint sv2 = s_sv[hw][e + 4],  sv3 = s_sv[hw][e + 6];
      uint sv4 = s_sv[hw][e + 8],  sv5 = s_sv[hw][e + 10];
      uint sv6 = s_sv[hw][e + 12], sv7 = s_sv[hw][e + 14];
      U2H a0, a1, a2, a3, a4, a5, a6, a7;
      a0.u = s_al[hw][e];      a1.u = s_al[hw][e + 2];
      a2.u = s_al[hw][e + 4];  a3.u = s_al[hw][e + 6];
      a4.u = s_al[hw][e + 8];  a5.u = s_al[hw][e + 10];
      a6.u = s_al[hw][e + 12]; a7.u = s_al[hw][e + 14];
      if (act) {
        uint2 hv0 = *(const uint2*)(hb + (sv0 * 40u + cqb));
        uint2 hv1 = *(const uint2*)(hb + (sv1 * 40u + cqb));
        uint2 hv2 = *(const uint2*)(hb + (sv2 * 40u + cqb));
        uint2 hv3 = *(const uint2*)(hb + (sv3 * 40u + cqb));
        uint2 hv4 = *(const uint2*)(hb + (sv4 * 40u + cqb));
        uint2 hv5 = *(const uint2*)(hb + (sv5 * 40u + cqb));
        uint2 hv6 = *(const uint2*)(hb + (sv6 * 40u + cqb));
        uint2 hv7 = *(const uint2*)(hb + (sv7 * 40u + cqb));
        U2H v;
        v.u = hv0.x; accA[0] = __hfma2(a0.h, v.h, accA[0]);
        v.u = hv0.y; accA[1] = __hfma2(a0.h, v.h, accA[1]);
        v.u = hv1.x; accB[0] = __hfma2(a1.h, v.h, accB[0]);
        v.u = hv1.y; accB[1] = __hfma2(a1.h, v.h, accB[1]);
        v.u = hv2.x; accA[0] = __hfma2(a2.h, v.h, accA[0]);
        v.u = hv2.y; accA[1] = __hfma2(a2.h, v.h, accA[1]);
        v.u = hv3.x; accB[0] = __hfma2(a3.h, v.h, accB[0]);
        v.u = hv3.y; accB[1] = __hfma2(a3.h, v.h, accB[1]);
        v.u = hv4.x; accA[0] = __hfma2(a4.h, v.h, accA[0]);
        v.u = hv4.y; accA[1] = __hfma2(a4.h, v.h, accA[1]);
        v.u = hv5.x; accB[0] = __hfma2(a5.h, v.h, accB[0]);
        v.u = hv5.y; accB[1] = __hfma2(a5.h, v.h, accB[1]);
        v.u = hv6.x; accA[0] = __hfma2(a6.h, v.h, accA[0]);
        v.u = hv6.y; accA[1] = __hfma2(a6.h, v.h, accA[1]);
        v.u = hv7.x; accB[0] = __hfma2(a7.h, v.h, accB[0]);
        v.u = hv7.y; accB[1] = __hfma2(a7.h, v.h, accB[1]);
      }
    }
    for (; e + 6 < cnt; e += 8) {
      uint sv0 = s_sv[hw][e],     sv1 = s_sv[hw][e + 2];
      uint sv2 = s_sv[hw][e + 4], sv3 = s_sv[hw][e + 6];
      U2H a0, a1, a2, a3;
      a0.u = s_al[hw][e];     a1.u = s_al[hw][e + 2];
      a2.u = s_al[hw][e + 4]; a3.u = s_al[hw][e + 6];
      if (act) {
        uint2 hv0 = *(const uint2*)(hb + (sv0 * 40u + cqb));
        uint2 hv1 = *(const uint2*)(hb + (sv1 * 40u + cqb));
        uint2 hv2 = *(const uint2*)(hb + (sv2 * 40u + cqb));
        uint2 hv3 = *(const uint2*)(hb + (sv3 * 40u + cqb));
        U2H v;
        v.u = hv0.x; accA[0] = __hfma2(a0.h, v.h, accA[0]);
        v.u = hv0.y; accA[1] = __hfma2(a0.h, v.h, accA[1]);
        v.u = hv1.x; accB[0] = __hfma2(a1.h, v.h, accB[0]);
        v.u = hv1.y; accB[1] = __hfma2(a1.h, v.h, accB[1]);
        v.u = hv2.x; accA[0] = __hfma2(a2.h, v.h, accA[0]);
        v.u = hv2.y; accA[1] = __hfma2(a2.h, v.h, accA[1]);
        v.u = hv3.x; accB[0] = __hfma2(a3.h, v.h, accB[0]);
        v.u = hv3.y; accB[1] = __hfma2(a3.h, v.h, accB[1]);
      }
    }
    for (; e < cnt; e += 2) {
      uint sv = s_sv[hw][e];
      U2H a0; a0.u = s_al[hw][e];
      if (act) {
        uint2 hv = *(const uint2*)(hb + (sv * 40u + cqb));
        U2H v;
        v.u = hv.x; accA[0] = __hfma2(a0.h, v.h, accA[0]);
        v.u = hv.y; accA[1] = __hfma2(a0.h, v.h, accA[1]);
      }
    }
  }
#pragma unroll
  for (int off = 1; off <= 16; off <<= 1) sacc += __shfl_xor(sacc, off);
  float invs = 1.f / sacc;
  float vv[4];
#pragma unroll
  for (int j = 0; j < 2; ++j) {
    U2H t; t.h = __hadd2(accA[j], accB[j]);
    U2H o; o.u = __shfl_xor(t.u, 16);
    t.h = __hadd2(t.h, o.h);
    vv[j * 2]     = __low2float(t.h) * invs;
    vv[j * 2 + 1] = __high2float(t.h) * invs;
  }
  float mm = -1e30f;
  if (act) {
#pragma unroll
    for (int j = 0; j < 4; ++j) {
      vv[j] += bias[cq * 4 + j];
      mm = fmaxf(mm, vv[j]);
    }
  }
#pragma unroll
  for (int off = 1; off <= 8; off <<= 1) mm = fmaxf(mm, __shfl_xor(mm, off));
  float se = 0.f;
  if (act) {
#pragma unroll
    for (int j = 0; j < 4; ++j) se += __expf(vv[j] - mm);
  }
#pragma unroll
  for (int off = 1; off <= 8; off <<= 1) se += __shfl_xor(se, off);
  if (act && p == 0) {
    float lse = mm + __logf(se);
    float4 o;
    o.x = vv[0] - lse; o.y = vv[1] - lse; o.z = vv[2] - lse; o.w = vv[3] - lse;
    *(float4*)&out[(size_t)node * 40 + cq * 4] = o;
  }
}

// ---------------- launch ----------------
extern "C" void kernel_launch(void* const* d_in, const int* in_sizes, int n_in,
                              void* d_out, int out_size, void* d_ws, size_t ws_size,
                              hipStream_t stream) {
  const float* x   = (const float*)d_in[0];
  const int*   ei  = (const int*)d_in[1];
  const float* W0  = (const float*)d_in[2];
  const float* as0 = (const float*)d_in[3];
  const float* ad0 = (const float*)d_in[4];
  const float* b0  = (const float*)d_in[5];
  const float* W1  = (const float*)d_in[6];
  const float* as1 = (const float*)d_in[7];
  const float* ad1 = (const float*)d_in[8];
  const float* b1  = (const float*)d_in[9];
  const float* W2  = (const float*)d_in[10];
  const float* as2 = (const float*)d_in[11];
  const float* ad2 = (const float*)d_in[12];
  const float* b2  = (const float*)d_in[13];
  float* out = (float*)d_out;

  char* p = (char*)d_ws;
  auto take = [&](size_t bytes) {
    char* q = p;
    p += (bytes + 255) & ~(size_t)255;
    return (void*)q;
  };
  ushort* xb0 = (ushort*)take((size_t)NODES * 128 * 2);
  ushort* xb1 = (ushort*)take((size_t)NODES * 256 * 2);
  ushort* xb2 = (ushort*)take((size_t)NODES * 256 * 2);
  ushort* hb  = (ushort*)take((size_t)NODES * 256 * 2);
  float* als  = (float*)take((size_t)NODES * 4 * 4);
  float* ald  = (float*)take((size_t)NODES * 4 * 4);
  ushort* ssrc= (ushort*)take((size_t)TOT_E * 2);
  int* offs   = (int*)take((size_t)(NODES + 1) * 4);
  int* cur    = (int*)take((size_t)NODES * 4);
  int* cnt    = (int*)take((size_t)(NODES + 64) * 4);
  int* done   = cnt + NODES;
  int* bsum   = (int*)take((size_t)SCAN_NB * 4);
  int* bpre   = (int*)take((size_t)SCAN_NB * 4);
  ushort* Bp0 = (ushort*)take((size_t)4 * 16 * 512 * 2);
  ushort* Bp1 = (ushort*)take((size_t)8 * 16 * 512 * 2);
  ushort* Bp2 = (ushort*)take((size_t)8 * 3 * 512 * 2);

  hipMemsetAsync(cnt, 0, (size_t)(NODES + 64) * 4, stream);
  k_setup<<<4096, 256, 0, stream>>>(ei + NEDGES, cnt, x, xb0, W0, Bp0, W1, Bp1, W2, Bp2);
  k_scan_red_part<<<SCAN_NB, SCAN_B, 0, stream>>>(cnt, bsum, bpre, done);
  k_scan_emit<<<SCAN_NB, SCAN_B, 0, stream>>>(cnt, bpre, offs, cur);
  k_scatter<<<4096, 256, 0, stream>>>(ei, ei + NEDGES, cur, ssrc);

  int nab = (NODES * 32 + 255) / 256;            // 6250 node-blocks (8 nodes each)
  int nab4 = (nab + 3) & ~3;                     // round to 4 for the 8-way mapping
  int nagg4 = nab4 * 2;                          // x2 channel halves

  // layer 0
  k_gemm_reg<4, 4, 4, 4, 16><<<512, 256, 0, stream>>>(xb0, Bp0, hb, as0, ad0, als, ald, NODES, 256, 128);
  k_agg4<<<nagg4, 256, 0, stream>>>(hb, als, ald, offs, ssrc, b0, xb1);

  // layer 1
  k_gemm_reg<8, 4, 4, 4, 16><<<512, 256, 0, stream>>>(xb1, Bp1, hb, as1, ad1, als, ald, NODES, 256, 256);
  k_agg4<<<nagg4, 256, 0, stream>>>(hb, als, ald, offs, ssrc, b1, xb2);

  // layer 2
  k_gemm_reg<8, 3, 1, 1, 3><<<512, 256, 0, stream>>>(xb2, Bp2, hb, as2, ad2, als, ald, NODES, 40, 256);
  k_agg1<<<nab, 256, 0, stream>>>(hb, als, ald, offs, ssrc, b2, out);
}